// Round 17
// baseline (284.373 us; speedup 1.0000x reference)
//
#include <hip/hip_runtime.h>
#include <hip/hip_fp16.h>
#include <math.h>

#define N_NODES 100000
#define N_EDGES 1600000
#define NEG_SLOPE 0.2f

#define BKT 256                             // nodes per bucket
#define NB ((N_NODES + BKT - 1) / BKT)      // 391 level-1 buckets
#define NC 1024                             // edge chunks
#define CHUNK ((N_EDGES + NC - 1) / NC)     // 1563 edges per chunk

#define WT_STRIDE 136                       // halves: 272B rows -> 8B-aligned frags
#define CS_STRIDE 136

typedef _Float16 f16x2 __attribute__((ext_vector_type(2)));
typedef _Float16 f16x4 __attribute__((ext_vector_type(4)));
typedef float f32x4v __attribute__((ext_vector_type(4)));

#define MFMA16(a, b, c) __builtin_amdgcn_mfma_f32_16x16x16f16(a, b, c, 0, 0, 0)

__device__ __forceinline__ float lrelu(float x) { return x > 0.f ? x : NEG_SLOPE * x; }
__device__ __forceinline__ float eluf(float x)  { return x > 0.f ? x : expm1f(x); }

// ======== atomic-free CSR build: two-level counting sort by dst ========

__global__ __launch_bounds__(256) void p1_hist(const int* __restrict__ dst,
                                               int* __restrict__ H) {
  __shared__ int hist[NB];
  int c = blockIdx.x, t = threadIdx.x;
  for (int i = t; i < NB; i += 256) hist[i] = 0;
  __syncthreads();
  int e0 = c * CHUNK, e1 = min(e0 + CHUNK, N_EDGES);
  for (int e = e0 + t; e < e1; e += 256) atomicAdd(&hist[dst[e] >> 8], 1);
  __syncthreads();
  for (int i = t; i < NB; i += 256) H[i * NC + c] = hist[i];
}

// per-bucket exclusive scan over NC=1024 chunks: 256 threads x int4
__global__ __launch_bounds__(256) void p2_colscan(int* __restrict__ H,
                                                  int* __restrict__ colTotal) {
  __shared__ int sh[256];
  int b = blockIdx.x, t = threadIdx.x;
  int4 v = *(int4*)&H[b * NC + t * 4];
  int tsum = v.x + v.y + v.z + v.w;
  sh[t] = tsum;
  __syncthreads();
  for (int off = 1; off < 256; off <<= 1) {
    int u = (t >= off) ? sh[t - off] : 0;
    __syncthreads();
    sh[t] += u;
    __syncthreads();
  }
  int excl = sh[t] - tsum;
  int4 o;
  o.x = excl;
  o.y = excl + v.x;
  o.z = o.y + v.y;
  o.w = o.z + v.z;
  *(int4*)&H[b * NC + t * 4] = o;
  if (t == 255) colTotal[b] = sh[255];
}

__global__ __launch_bounds__(512) void p3_bucketscan(const int* __restrict__ colTotal,
                                                     int* __restrict__ bucketBase) {
  __shared__ int sh[512];
  int t = threadIdx.x;
  int v = (t < NB) ? colTotal[t] : 0;
  sh[t] = v;
  __syncthreads();
  for (int off = 1; off < 512; off <<= 1) {
    int u = (t >= off) ? sh[t - off] : 0;
    __syncthreads();
    sh[t] += u;
    __syncthreads();
  }
  if (t < NB) bucketBase[t] = sh[t] - v;
  if (t == NB - 1) bucketBase[NB] = sh[t];  // == N_EDGES
}

// tmp packs (src << 8) | (dst & 255): src < 2^24 so it fits one int
__global__ __launch_bounds__(256) void p4_scatter(const int* __restrict__ src,
                                                  const int* __restrict__ dst,
                                                  const int* __restrict__ H,
                                                  const int* __restrict__ bucketBase,
                                                  int* __restrict__ tmp) {
  __shared__ int cur[NB];
  int c = blockIdx.x, t = threadIdx.x;
  for (int i = t; i < NB; i += 256) cur[i] = bucketBase[i] + H[i * NC + c];
  __syncthreads();
  int e0 = c * CHUNK, e1 = min(e0 + CHUNK, N_EDGES);
  for (int e = e0 + t; e < e1; e += 256) {
    int d = dst[e];
    int pos = atomicAdd(&cur[d >> 8], 1);
    tmp[pos] = (src[e] << 8) | (d & 255);
  }
}

__global__ __launch_bounds__(256) void p5_build(const int* __restrict__ tmp,
                                                const int* __restrict__ bucketBase,
                                                int* __restrict__ rowstart,
                                                int* __restrict__ csr_src) {
  __shared__ int hist[256];
  __shared__ int sh[256];
  __shared__ int cur[256];
  int b = blockIdx.x, t = threadIdx.x;
  int ebase = bucketBase[b], eend = bucketBase[b + 1];
  hist[t] = 0;
  __syncthreads();
  for (int e = ebase + t; e < eend; e += 256) atomicAdd(&hist[tmp[e] & 255], 1);
  __syncthreads();
  int v = hist[t];
  sh[t] = v;
  __syncthreads();
  for (int off = 1; off < 256; off <<= 1) {
    int u = (t >= off) ? sh[t - off] : 0;
    __syncthreads();
    sh[t] += u;
    __syncthreads();
  }
  int excl = sh[t] - v;
  int node = b * 256 + t;
  if (node < N_NODES) rowstart[node] = ebase + excl;
  cur[t] = excl;
  __syncthreads();
  for (int e = ebase + t; e < eend; e += 256) {
    int p = tmp[e];
    int pos = ebase + atomicAdd(&cur[p & 255], 1);
    csr_src[pos] = p >> 8;
  }
  if (b == 0 && t == 0) rowstart[N_NODES] = N_EDGES;
}

// ======== MFMA GEMM: Chalf[N,128] = A[N,128] @ W[128,128], fused el/er ========
template <bool FP16IN>
__global__ __launch_bounds__(256) void gemm128_mfma(const void* __restrict__ Av,
                                                    const float* __restrict__ W,
                                                    const float* __restrict__ al,
                                                    const float* __restrict__ ar,
                                                    __half* __restrict__ C,
                                                    float* __restrict__ el,
                                                    float* __restrict__ er, int N) {
  __shared__ _Float16 WtCs[128 * WT_STRIDE];   // Wt[c][k]; reused as Cs[row][col]
  __shared__ float als[128], ars[128];
  int tid = threadIdx.x;
  int wv = tid >> 6;
  int l = tid & 63;
  int li = l & 15, lk = l >> 4;
  int rowBase = blockIdx.x * 64;

  if (tid < 128) { als[tid] = al[tid]; ars[tid] = ar[tid]; }

#pragma unroll 4
  for (int i = 0; i < 32; i++) {
    int idx = tid + 256 * i;
    int c = idx & 127, k = (idx >> 7) * 2;
    f16x2 p;
    p[0] = (_Float16)W[k * 128 + c];
    p[1] = (_Float16)W[(k + 1) * 128 + c];
    *(f16x2*)&WtCs[c * WT_STRIDE + k] = p;
  }

  f16x4 afr[8];
  int ra = min(rowBase + wv * 16 + li, N - 1);
  if constexpr (FP16IN) {
    const _Float16* A = (const _Float16*)Av;
#pragma unroll
    for (int ch = 0; ch < 8; ch++)
      afr[ch] = *(const f16x4*)&A[(size_t)ra * 128 + ch * 16 + lk * 4];
  } else {
    const float* A = (const float*)Av;
#pragma unroll
    for (int ch = 0; ch < 8; ch++) {
      float4 v = *(const float4*)&A[(size_t)ra * 128 + ch * 16 + lk * 4];
      f16x4 a;
      a[0] = (_Float16)v.x; a[1] = (_Float16)v.y;
      a[2] = (_Float16)v.z; a[3] = (_Float16)v.w;
      afr[ch] = a;
    }
  }
  __syncthreads();

  f32x4v acc[8];
#pragma unroll
  for (int ct = 0; ct < 8; ct++) acc[ct] = (f32x4v){0.f, 0.f, 0.f, 0.f};

#pragma unroll
  for (int ch = 0; ch < 8; ch++) {
#pragma unroll
    for (int ct = 0; ct < 8; ct++) {
      f16x4 b = *(const f16x4*)&WtCs[(ct * 16 + li) * WT_STRIDE + ch * 16 + lk * 4];
      acc[ct] = MFMA16(afr[ch], b, acc[ct]);
    }
  }

  float alc[8], arc[8];
#pragma unroll
  for (int ct = 0; ct < 8; ct++) {
    alc[ct] = als[ct * 16 + li];
    arc[ct] = ars[ct * 16 + li];
  }
#pragma unroll
  for (int j = 0; j < 4; j++) {
    float el4[4], er4[4];
#pragma unroll
    for (int hh = 0; hh < 4; hh++) {
      el4[hh] = acc[2 * hh][j] * alc[2 * hh] + acc[2 * hh + 1][j] * alc[2 * hh + 1];
      er4[hh] = acc[2 * hh][j] * arc[2 * hh] + acc[2 * hh + 1][j] * arc[2 * hh + 1];
    }
#pragma unroll
    for (int m = 1; m < 16; m <<= 1) {
#pragma unroll
      for (int hh = 0; hh < 4; hh++) {
        el4[hh] += __shfl_xor(el4[hh], m, 64);
        er4[hh] += __shfl_xor(er4[hh], m, 64);
      }
    }
    int row = rowBase + wv * 16 + lk * 4 + j;
    if (li == 0 && row < N) {
      *(float4*)&el[row * 4] = make_float4(el4[0], el4[1], el4[2], el4[3]);
      *(float4*)&er[row * 4] = make_float4(er4[0], er4[1], er4[2], er4[3]);
    }
  }

  __syncthreads();   // all waves done reading Wt
#pragma unroll
  for (int j = 0; j < 4; j++) {
    int rl = wv * 16 + lk * 4 + j;
#pragma unroll
    for (int ct = 0; ct < 8; ct++)
      WtCs[rl * CS_STRIDE + ct * 16 + li] = (_Float16)acc[ct][j];
  }
  __syncthreads();
  int rrow = tid >> 2, ckk = tid & 3;
  int grow = rowBase + rrow;
  if (grow < N) {
#pragma unroll
    for (int q = 0; q < 4; q++) {
      float4 v = *(float4*)&WtCs[rrow * CS_STRIDE + ckk * 32 + q * 8];
      *(float4*)&C[(size_t)grow * 128 + ckk * 32 + q * 8] = v;
    }
  }
}

// ==== fused softmax+aggregation, feature-half split pinned to XCD groups ====
// Grid = 8 * ceil(NG/4) blocks; r=blockIdx&7 -> XCD (round-robin dispatch);
// half = r>>2 (features half*64..+64), node group ng = (blockIdx>>3)*4 + (r&3).
// Each XCD touches only its half of every h row -> per-XCD h traffic halves.
// Score phase (csr+el+exp) recomputed identically per half (fp32, bit-same).
__global__ __launch_bounds__(256) void agg_fused(const __half* __restrict__ h,
                                                 const float* __restrict__ el,
                                                 const float* __restrict__ er,
                                                 const int* __restrict__ rowstart,
                                                 const int* __restrict__ csr_src,
                                                 const float* __restrict__ bias,
                                                 __half* __restrict__ out, int NG) {
  __shared__ float wlds[16][17][4];
  __shared__ int   ilds[16][17];
  int tid = threadIdx.x;
  int r = blockIdx.x & 7;
  int half = r >> 2;
  int ng = (blockIdx.x >> 3) * 4 + (r & 3);
  if (ng >= NG) return;
  int slot = tid >> 4;
  int l = tid & 15;
  int n = ng * 16 + slot;
  if (n >= N_NODES) return;
  int base = rowstart[n];
  int deg = rowstart[n + 1] - base;
  int f0 = half * 64 + l * 4;         // 4 fp16 features per lane
  int head = (half << 1) | (l >> 3);
  float acc[4] = {};
  float lsum = 0.f;

  if (deg > 0) {
    float4 erv = *(const float4*)&er[n * 4];

    for (int t0 = 0; t0 < deg; t0 += 16) {
      int e = t0 + l;
      bool act = e < deg;
      int s = act ? csr_src[base + e] : 0;
      float4 elv = *(const float4*)&el[s * 4];
      float w0 = act ? __expf(fminf(lrelu(elv.x + erv.x), 30.f)) : 0.f;
      float w1 = act ? __expf(fminf(lrelu(elv.y + erv.y), 30.f)) : 0.f;
      float w2 = act ? __expf(fminf(lrelu(elv.z + erv.z), 30.f)) : 0.f;
      float w3 = act ? __expf(fminf(lrelu(elv.w + erv.w), 30.f)) : 0.f;
      *(float4*)&wlds[slot][l][0] = make_float4(w0, w1, w2, w3);
      ilds[slot][l] = s;
      __builtin_amdgcn_wave_barrier();

      int nt = min(16, deg - t0);
#pragma unroll 4
      for (int i = 0; i < nt; i++) {
        int si = ilds[slot][i];
        float wi = wlds[slot][i][head];
        lsum += wi;
        float2 raw = *(const float2*)&h[(size_t)si * 128 + f0];  // 4 halfs
        const __half2* hp = (const __half2*)&raw;
        float2 c0 = __half22float2(hp[0]);
        float2 c1 = __half22float2(hp[1]);
        acc[0] = fmaf(c0.x, wi, acc[0]); acc[1] = fmaf(c0.y, wi, acc[1]);
        acc[2] = fmaf(c1.x, wi, acc[2]); acc[3] = fmaf(c1.y, wi, acc[3]);
      }
      __builtin_amdgcn_wave_barrier();
    }
    float rh = 1.f / lsum;
#pragma unroll
    for (int j = 0; j < 4; j++) acc[j] *= rh;
  }
  float4 b0 = *(const float4*)&bias[f0];
  float r0 = eluf(acc[0] + b0.x), r1 = eluf(acc[1] + b0.y);
  float r2 = eluf(acc[2] + b0.z), r3 = eluf(acc[3] + b0.w);
  __half2 pk[2];
  pk[0] = __float22half2_rn(make_float2(r0, r1));
  pk[1] = __float22half2_rn(make_float2(r2, r3));
  *(float2*)&out[(size_t)n * 128 + f0] = *(float2*)pk;   // 4 halfs = 8 B
}

// ======== final linear (MFMA): C[N,40] = Ahalf[N,128] @ Wo[128,40] + bo ========
__global__ __launch_bounds__(256) void gemm_out_k(const __half* __restrict__ A,
                                                  const float* __restrict__ Wo,
                                                  const float* __restrict__ bo,
                                                  float* __restrict__ C, int N) {
  __shared__ _Float16 WoT[48 * WT_STRIDE];   // WoT[c][k], c padded 40->48
  int tid = threadIdx.x;
  int wv = tid >> 6;
  int l = tid & 63;
  int li = l & 15, lk = l >> 4;
  int rowBase = blockIdx.x * 64;

#pragma unroll
  for (int i = 0; i < 12; i++) {
    int idx = tid + 256 * i;          // 0..3071
    int c = idx >> 6, k2 = (idx & 63) * 2;
    f16x2 p;
    p[0] = (c < 40) ? (_Float16)Wo[k2 * 40 + c] : (_Float16)0.f;
    p[1] = (c < 40) ? (_Float16)Wo[(k2 + 1) * 40 + c] : (_Float16)0.f;
    *(f16x2*)&WoT[c * WT_STRIDE + k2] = p;
  }

  f16x4 afr[8];
  int ra = min(rowBase + wv * 16 + li, N - 1);
  const _Float16* Ah = (const _Float16*)A;
#pragma unroll
  for (int ch = 0; ch < 8; ch++)
    afr[ch] = *(const f16x4*)&Ah[(size_t)ra * 128 + ch * 16 + lk * 4];
  __syncthreads();

  f32x4v acc[3];
#pragma unroll
  for (int ct = 0; ct < 3; ct++) acc[ct] = (f32x4v){0.f, 0.f, 0.f, 0.f};

#pragma unroll
  for (int ch = 0; ch < 8; ch++) {
#pragma unroll
    for (int ct = 0; ct < 3; ct++) {
      f16x4 b = *(const f16x4*)&WoT[(ct * 16 + li) * WT_STRIDE + ch * 16 + lk * 4];
      acc[ct] = MFMA16(afr[ch], b, acc[ct]);
    }
  }

#pragma unroll
  for (int ct = 0; ct < 3; ct++) {
    int col = ct * 16 + li;
    if (col < 40) {
      float bv = bo[col];
#pragma unroll
      for (int j = 0; j < 4; j++) {
        int row = rowBase + wv * 16 + lk * 4 + j;
        if (row < N) C[(size_t)row * 40 + col] = acc[ct][j] + bv;
      }
    }
  }
}

extern "C" void kernel_launch(void* const* d_in, const int* in_sizes, int n_in,
                              void* d_out, int out_size, void* d_ws, size_t ws_size,
                              hipStream_t stream) {
  const float* x    = (const float*)d_in[0];
  const int*   src  = (const int*)d_in[1];
  const int*   dst  = (const int*)d_in[2];
  const float* W1   = (const float*)d_in[3];
  const float* al1  = (const float*)d_in[4];
  const float* ar1  = (const float*)d_in[5];
  const float* b1   = (const float*)d_in[6];
  const float* W2   = (const float*)d_in[7];
  const float* al2  = (const float*)d_in[8];
  const float* ar2  = (const float*)d_in[9];
  const float* b2   = (const float*)d_in[10];
  const float* Wout = (const float*)d_in[11];
  const float* bout = (const float*)d_in[12];
  float* out = (float*)d_out;

  const int N = N_NODES, E = N_EDGES;
  size_t off = 0;
  auto alloc = [&](size_t bytes) {
    void* p = (char*)d_ws + off;
    off += (bytes + 255) & ~(size_t)255;
    return p;
  };
  __half* hh  = (__half*)alloc((size_t)N * 128 * 2);
  __half* o16 = (__half*)alloc((size_t)N * 128 * 2);
  float* el  = (float*)alloc((size_t)N * 4 * 4);
  float* er  = (float*)alloc((size_t)N * 4 * 4);
  int* rowstart   = (int*)alloc((size_t)(N + 1) * 4);
  int* H          = (int*)alloc((size_t)NB * NC * 4);
  int* colTotal   = (int*)alloc((size_t)NB * 4);
  int* bucketBase = (int*)alloc((size_t)(NB + 1) * 4);
  int* tmp        = (int*)alloc((size_t)E * 4);
  int* csr_src    = (int*)alloc((size_t)E * 4);
  (void)ws_size; (void)in_sizes; (void)n_in; (void)out_size;

  // CSR build (atomic-free counting sort)
  p1_hist<<<NC, 256, 0, stream>>>(dst, H);
  p2_colscan<<<NB, 256, 0, stream>>>(H, colTotal);
  p3_bucketscan<<<1, 512, 0, stream>>>(colTotal, bucketBase);
  p4_scatter<<<NC, 256, 0, stream>>>(src, dst, H, bucketBase, tmp);
  p5_build<<<NB, 256, 0, stream>>>(tmp, bucketBase, rowstart, csr_src);

  int gemmGrid = (N + 63) / 64;
  int outGrid  = (N + 63) / 64;
  int NG = (N + 15) / 16;                       // 16-node groups
  int aggGrid = ((NG + 3) / 4) * 8;             // 2 halves x NG, XCD-pinned

  // layer 1 (fp32 input x)
  gemm128_mfma<false><<<gemmGrid, 256, 0, stream>>>(x, W1, al1, ar1, hh, el, er, N);
  agg_fused<<<aggGrid, 256, 0, stream>>>(hh, el, er, rowstart, csr_src, b1, o16, NG);

  // layer 2 (fp16 input o16)
  gemm128_mfma<true><<<gemmGrid, 256, 0, stream>>>(o16, W2, al2, ar2, hh, el, er, N);
  agg_fused<<<aggGrid, 256, 0, stream>>>(hh, el, er, rowstart, csr_src, b2, o16, NG);

  // output linear (fp16 input, MFMA)
  gemm_out_k<<<outGrid, 256, 0, stream>>>(o16, Wout, bout, out, N);
}

// Round 18
// 278.948 us; speedup vs baseline: 1.0194x; 1.0194x over previous
//
#include <hip/hip_runtime.h>
#include <hip/hip_fp16.h>
#include <math.h>

#define N_NODES 100000
#define N_EDGES 1600000
#define NEG_SLOPE 0.2f

#define BKT 256                             // nodes per bucket
#define NB ((N_NODES + BKT - 1) / BKT)      // 391 level-1 buckets
#define NC 1024                             // edge chunks
#define CHUNK ((N_EDGES + NC - 1) / NC)     // 1563 edges per chunk

#define WT_STRIDE 136                       // halves: 272B rows -> 8B-aligned frags
#define CS_STRIDE 136

typedef _Float16 f16x2 __attribute__((ext_vector_type(2)));
typedef _Float16 f16x4 __attribute__((ext_vector_type(4)));
typedef float f32x4v __attribute__((ext_vector_type(4)));

#define MFMA16(a, b, c) __builtin_amdgcn_mfma_f32_16x16x16f16(a, b, c, 0, 0, 0)

__device__ __forceinline__ float lrelu(float x) { return x > 0.f ? x : NEG_SLOPE * x; }
__device__ __forceinline__ float eluf(float x)  { return x > 0.f ? x : expm1f(x); }

// ======== atomic-free CSR build: two-level counting sort by dst ========

__global__ __launch_bounds__(256) void p1_hist(const int* __restrict__ dst,
                                               int* __restrict__ H) {
  __shared__ int hist[NB];
  int c = blockIdx.x, t = threadIdx.x;
  for (int i = t; i < NB; i += 256) hist[i] = 0;
  __syncthreads();
  int e0 = c * CHUNK, e1 = min(e0 + CHUNK, N_EDGES);
  for (int e = e0 + t; e < e1; e += 256) atomicAdd(&hist[dst[e] >> 8], 1);
  __syncthreads();
  for (int i = t; i < NB; i += 256) H[i * NC + c] = hist[i];
}

// per-bucket exclusive scan over NC=1024 chunks: 256 threads x int4
__global__ __launch_bounds__(256) void p2_colscan(int* __restrict__ H,
                                                  int* __restrict__ colTotal) {
  __shared__ int sh[256];
  int b = blockIdx.x, t = threadIdx.x;
  int4 v = *(int4*)&H[b * NC + t * 4];
  int tsum = v.x + v.y + v.z + v.w;
  sh[t] = tsum;
  __syncthreads();
  for (int off = 1; off < 256; off <<= 1) {
    int u = (t >= off) ? sh[t - off] : 0;
    __syncthreads();
    sh[t] += u;
    __syncthreads();
  }
  int excl = sh[t] - tsum;
  int4 o;
  o.x = excl;
  o.y = excl + v.x;
  o.z = o.y + v.y;
  o.w = o.z + v.z;
  *(int4*)&H[b * NC + t * 4] = o;
  if (t == 255) colTotal[b] = sh[255];
}

__global__ __launch_bounds__(512) void p3_bucketscan(const int* __restrict__ colTotal,
                                                     int* __restrict__ bucketBase) {
  __shared__ int sh[512];
  int t = threadIdx.x;
  int v = (t < NB) ? colTotal[t] : 0;
  sh[t] = v;
  __syncthreads();
  for (int off = 1; off < 512; off <<= 1) {
    int u = (t >= off) ? sh[t - off] : 0;
    __syncthreads();
    sh[t] += u;
    __syncthreads();
  }
  if (t < NB) bucketBase[t] = sh[t] - v;
  if (t == NB - 1) bucketBase[NB] = sh[t];  // == N_EDGES
}

// tmp packs (src << 8) | (dst & 255): src < 2^24 so it fits one int
__global__ __launch_bounds__(256) void p4_scatter(const int* __restrict__ src,
                                                  const int* __restrict__ dst,
                                                  const int* __restrict__ H,
                                                  const int* __restrict__ bucketBase,
                                                  int* __restrict__ tmp) {
  __shared__ int cur[NB];
  int c = blockIdx.x, t = threadIdx.x;
  for (int i = t; i < NB; i += 256) cur[i] = bucketBase[i] + H[i * NC + c];
  __syncthreads();
  int e0 = c * CHUNK, e1 = min(e0 + CHUNK, N_EDGES);
  for (int e = e0 + t; e < e1; e += 256) {
    int d = dst[e];
    int pos = atomicAdd(&cur[d >> 8], 1);
    tmp[pos] = (src[e] << 8) | (d & 255);
  }
}

__global__ __launch_bounds__(256) void p5_build(const int* __restrict__ tmp,
                                                const int* __restrict__ bucketBase,
                                                int* __restrict__ rowstart,
                                                int* __restrict__ csr_src) {
  __shared__ int hist[256];
  __shared__ int sh[256];
  __shared__ int cur[256];
  int b = blockIdx.x, t = threadIdx.x;
  int ebase = bucketBase[b], eend = bucketBase[b + 1];
  hist[t] = 0;
  __syncthreads();
  for (int e = ebase + t; e < eend; e += 256) atomicAdd(&hist[tmp[e] & 255], 1);
  __syncthreads();
  int v = hist[t];
  sh[t] = v;
  __syncthreads();
  for (int off = 1; off < 256; off <<= 1) {
    int u = (t >= off) ? sh[t - off] : 0;
    __syncthreads();
    sh[t] += u;
    __syncthreads();
  }
  int excl = sh[t] - v;
  int node = b * 256 + t;
  if (node < N_NODES) rowstart[node] = ebase + excl;
  cur[t] = excl;
  __syncthreads();
  for (int e = ebase + t; e < eend; e += 256) {
    int p = tmp[e];
    int pos = ebase + atomicAdd(&cur[p & 255], 1);
    csr_src[pos] = p >> 8;
  }
  if (b == 0 && t == 0) rowstart[N_NODES] = N_EDGES;
}

// ======== MFMA GEMM: Chalf[N,128] = A[N,128] @ W[128,128], fused el/er ========
// 64 rows/block, 4 waves; wave wv owns rows wv*16..+16, all 128 cols (8 coltiles).
// Fragment layouts (AMD hello-mfma, m89-verified D):
//   A: row=l&15,  k=(l>>4)*4+i   B: col=l&15, k=(l>>4)*4+i
//   D: col=l&15, row=(l>>4)*4+reg
template <bool FP16IN>
__global__ __launch_bounds__(256) void gemm128_mfma(const void* __restrict__ Av,
                                                    const float* __restrict__ W,
                                                    const float* __restrict__ al,
                                                    const float* __restrict__ ar,
                                                    __half* __restrict__ C,
                                                    float* __restrict__ el,
                                                    float* __restrict__ er, int N) {
  __shared__ _Float16 WtCs[128 * WT_STRIDE];   // Wt[c][k]; reused as Cs[row][col]
  __shared__ float als[128], ars[128];
  int tid = threadIdx.x;
  int wv = tid >> 6;
  int l = tid & 63;
  int li = l & 15, lk = l >> 4;
  int rowBase = blockIdx.x * 64;

  if (tid < 128) { als[tid] = al[tid]; ars[tid] = ar[tid]; }

  // stage Wt[c][k] = fp16(W[k][c]); pairs along k (b32 writes), coalesced reads
#pragma unroll 4
  for (int i = 0; i < 32; i++) {
    int idx = tid + 256 * i;
    int c = idx & 127, k = (idx >> 7) * 2;
    f16x2 p;
    p[0] = (_Float16)W[k * 128 + c];
    p[1] = (_Float16)W[(k + 1) * 128 + c];
    *(f16x2*)&WtCs[c * WT_STRIDE + k] = p;
  }

  // A fragments: 8 K-chains x 4 halves, straight from global
  f16x4 afr[8];
  int ra = min(rowBase + wv * 16 + li, N - 1);
  if constexpr (FP16IN) {
    const _Float16* A = (const _Float16*)Av;
#pragma unroll
    for (int ch = 0; ch < 8; ch++)
      afr[ch] = *(const f16x4*)&A[(size_t)ra * 128 + ch * 16 + lk * 4];
  } else {
    const float* A = (const float*)Av;
#pragma unroll
    for (int ch = 0; ch < 8; ch++) {
      float4 v = *(const float4*)&A[(size_t)ra * 128 + ch * 16 + lk * 4];
      f16x4 a;
      a[0] = (_Float16)v.x; a[1] = (_Float16)v.y;
      a[2] = (_Float16)v.z; a[3] = (_Float16)v.w;
      afr[ch] = a;
    }
  }
  __syncthreads();

  f32x4v acc[8];
#pragma unroll
  for (int ct = 0; ct < 8; ct++) acc[ct] = (f32x4v){0.f, 0.f, 0.f, 0.f};

#pragma unroll
  for (int ch = 0; ch < 8; ch++) {
#pragma unroll
    for (int ct = 0; ct < 8; ct++) {
      f16x4 b = *(const f16x4*)&WtCs[(ct * 16 + li) * WT_STRIDE + ch * 16 + lk * 4];
      acc[ct] = MFMA16(afr[ch], b, acc[ct]);
    }
  }

  // fused el/er from accumulators (cols ct*16+li, rows wv*16+lk*4+j)
  float alc[8], arc[8];
#pragma unroll
  for (int ct = 0; ct < 8; ct++) {
    alc[ct] = als[ct * 16 + li];
    arc[ct] = ars[ct * 16 + li];
  }
#pragma unroll
  for (int j = 0; j < 4; j++) {
    float el4[4], er4[4];
#pragma unroll
    for (int hh = 0; hh < 4; hh++) {
      el4[hh] = acc[2 * hh][j] * alc[2 * hh] + acc[2 * hh + 1][j] * alc[2 * hh + 1];
      er4[hh] = acc[2 * hh][j] * arc[2 * hh] + acc[2 * hh + 1][j] * arc[2 * hh + 1];
    }
#pragma unroll
    for (int m = 1; m < 16; m <<= 1) {
#pragma unroll
      for (int hh = 0; hh < 4; hh++) {
        el4[hh] += __shfl_xor(el4[hh], m, 64);
        er4[hh] += __shfl_xor(er4[hh], m, 64);
      }
    }
    int row = rowBase + wv * 16 + lk * 4 + j;
    if (li == 0 && row < N) {
      *(float4*)&el[row * 4] = make_float4(el4[0], el4[1], el4[2], el4[3]);
      *(float4*)&er[row * 4] = make_float4(er4[0], er4[1], er4[2], er4[3]);
    }
  }

  // repack C through LDS (reuse Wt space) for coalesced fp16 stores
  __syncthreads();   // all waves done reading Wt
#pragma unroll
  for (int j = 0; j < 4; j++) {
    int rl = wv * 16 + lk * 4 + j;
#pragma unroll
    for (int ct = 0; ct < 8; ct++)
      WtCs[rl * CS_STRIDE + ct * 16 + li] = (_Float16)acc[ct][j];
  }
  __syncthreads();
  int rrow = tid >> 2, ckk = tid & 3;
  int grow = rowBase + rrow;
  if (grow < N) {
#pragma unroll
    for (int q = 0; q < 4; q++) {
      float4 v = *(float4*)&WtCs[rrow * CS_STRIDE + ckk * 32 + q * 8];
      *(float4*)&C[(size_t)grow * 128 + ckk * 32 + q * 8] = v;
    }
  }
}

// ==== fused softmax+aggregation: 4 nodes/wave, 16 lanes x 8 fp16 feats ====
__global__ __launch_bounds__(256) void agg_fused(const __half* __restrict__ h,
                                                 const float* __restrict__ el,
                                                 const float* __restrict__ er,
                                                 const int* __restrict__ rowstart,
                                                 const int* __restrict__ csr_src,
                                                 const float* __restrict__ bias,
                                                 __half* __restrict__ out) {
  __shared__ float wlds[16][17][4];
  __shared__ int   ilds[16][17];
  int tid = threadIdx.x;
  int slot = tid >> 4;
  int l = tid & 15;
  int n = blockIdx.x * 16 + slot;
  if (n >= N_NODES) return;
  int base = rowstart[n];
  int deg = rowstart[n + 1] - base;
  int f0 = l * 8;
  int head = l >> 2;
  float acc[8] = {};
  float lsum = 0.f;

  if (deg > 0) {
    float4 erv = *(const float4*)&er[n * 4];

    for (int t0 = 0; t0 < deg; t0 += 16) {
      int e = t0 + l;
      bool act = e < deg;
      int s = act ? csr_src[base + e] : 0;
      float4 elv = *(const float4*)&el[s * 4];
      float w0 = act ? __expf(fminf(lrelu(elv.x + erv.x), 30.f)) : 0.f;
      float w1 = act ? __expf(fminf(lrelu(elv.y + erv.y), 30.f)) : 0.f;
      float w2 = act ? __expf(fminf(lrelu(elv.z + erv.z), 30.f)) : 0.f;
      float w3 = act ? __expf(fminf(lrelu(elv.w + erv.w), 30.f)) : 0.f;
      *(float4*)&wlds[slot][l][0] = make_float4(w0, w1, w2, w3);
      ilds[slot][l] = s;
      __builtin_amdgcn_wave_barrier();

      int nt = min(16, deg - t0);
#pragma unroll 4
      for (int i = 0; i < nt; i++) {
        int si = ilds[slot][i];
        float wi = wlds[slot][i][head];
        lsum += wi;
        float4 raw = *(const float4*)&h[(size_t)si * 128 + f0];
        const __half2* hp = (const __half2*)&raw;
        float2 c0 = __half22float2(hp[0]);
        float2 c1 = __half22float2(hp[1]);
        float2 c2 = __half22float2(hp[2]);
        float2 c3 = __half22float2(hp[3]);
        acc[0] = fmaf(c0.x, wi, acc[0]); acc[1] = fmaf(c0.y, wi, acc[1]);
        acc[2] = fmaf(c1.x, wi, acc[2]); acc[3] = fmaf(c1.y, wi, acc[3]);
        acc[4] = fmaf(c2.x, wi, acc[4]); acc[5] = fmaf(c2.y, wi, acc[5]);
        acc[6] = fmaf(c3.x, wi, acc[6]); acc[7] = fmaf(c3.y, wi, acc[7]);
      }
      __builtin_amdgcn_wave_barrier();
    }
    float rh = 1.f / lsum;
#pragma unroll
    for (int j = 0; j < 8; j++) acc[j] *= rh;
  }
  float4 b0 = *(const float4*)&bias[f0];
  float4 b1 = *(const float4*)&bias[f0 + 4];
  float r0 = eluf(acc[0] + b0.x), r1 = eluf(acc[1] + b0.y);
  float r2 = eluf(acc[2] + b0.z), r3 = eluf(acc[3] + b0.w);
  float r4 = eluf(acc[4] + b1.x), r5 = eluf(acc[5] + b1.y);
  float r6 = eluf(acc[6] + b1.z), r7 = eluf(acc[7] + b1.w);
  __half2 pk[4];
  pk[0] = __float22half2_rn(make_float2(r0, r1));
  pk[1] = __float22half2_rn(make_float2(r2, r3));
  pk[2] = __float22half2_rn(make_float2(r4, r5));
  pk[3] = __float22half2_rn(make_float2(r6, r7));
  *(float4*)&out[(size_t)n * 128 + f0] = *(float4*)pk;
}

// ======== final linear (MFMA): C[N,40] = Ahalf[N,128] @ Wo[128,40] + bo ========
__global__ __launch_bounds__(256) void gemm_out_k(const __half* __restrict__ A,
                                                  const float* __restrict__ Wo,
                                                  const float* __restrict__ bo,
                                                  float* __restrict__ C, int N) {
  __shared__ _Float16 WoT[48 * WT_STRIDE];   // WoT[c][k], c padded 40->48
  int tid = threadIdx.x;
  int wv = tid >> 6;
  int l = tid & 63;
  int li = l & 15, lk = l >> 4;
  int rowBase = blockIdx.x * 64;

#pragma unroll
  for (int i = 0; i < 12; i++) {
    int idx = tid + 256 * i;          // 0..3071
    int c = idx >> 6, k2 = (idx & 63) * 2;
    f16x2 p;
    p[0] = (c < 40) ? (_Float16)Wo[k2 * 40 + c] : (_Float16)0.f;
    p[1] = (c < 40) ? (_Float16)Wo[(k2 + 1) * 40 + c] : (_Float16)0.f;
    *(f16x2*)&WoT[c * WT_STRIDE + k2] = p;
  }

  f16x4 afr[8];
  int ra = min(rowBase + wv * 16 + li, N - 1);
  const _Float16* Ah = (const _Float16*)A;
#pragma unroll
  for (int ch = 0; ch < 8; ch++)
    afr[ch] = *(const f16x4*)&Ah[(size_t)ra * 128 + ch * 16 + lk * 4];
  __syncthreads();

  f32x4v acc[3];
#pragma unroll
  for (int ct = 0; ct < 3; ct++) acc[ct] = (f32x4v){0.f, 0.f, 0.f, 0.f};

#pragma unroll
  for (int ch = 0; ch < 8; ch++) {
#pragma unroll
    for (int ct = 0; ct < 3; ct++) {
      f16x4 b = *(const f16x4*)&WoT[(ct * 16 + li) * WT_STRIDE + ch * 16 + lk * 4];
      acc[ct] = MFMA16(afr[ch], b, acc[ct]);
    }
  }

#pragma unroll
  for (int ct = 0; ct < 3; ct++) {
    int col = ct * 16 + li;
    if (col < 40) {
      float bv = bo[col];
#pragma unroll
      for (int j = 0; j < 4; j++) {
        int row = rowBase + wv * 16 + lk * 4 + j;
        if (row < N) C[(size_t)row * 40 + col] = acc[ct][j] + bv;
      }
    }
  }
}

extern "C" void kernel_launch(void* const* d_in, const int* in_sizes, int n_in,
                              void* d_out, int out_size, void* d_ws, size_t ws_size,
                              hipStream_t stream) {
  const float* x    = (const float*)d_in[0];
  const int*   src  = (const int*)d_in[1];
  const int*   dst  = (const int*)d_in[2];
  const float* W1   = (const float*)d_in[3];
  const float* al1  = (const float*)d_in[4];
  const float* ar1  = (const float*)d_in[5];
  const float* b1   = (const float*)d_in[6];
  const float* W2   = (const float*)d_in[7];
  const float* al2  = (const float*)d_in[8];
  const float* ar2  = (const float*)d_in[9];
  const float* b2   = (const float*)d_in[10];
  const float* Wout = (const float*)d_in[11];
  const float* bout = (const float*)d_in[12];
  float* out = (float*)d_out;

  const int N = N_NODES, E = N_EDGES;
  size_t off = 0;
  auto alloc = [&](size_t bytes) {
    void* p = (char*)d_ws + off;
    off += (bytes + 255) & ~(size_t)255;
    return p;
  };
  __half* hh  = (__half*)alloc((size_t)N * 128 * 2);
  __half* o16 = (__half*)alloc((size_t)N * 128 * 2);
  float* el  = (float*)alloc((size_t)N * 4 * 4);
  float* er  = (float*)alloc((size_t)N * 4 * 4);
  int* rowstart   = (int*)alloc((size_t)(N + 1) * 4);
  int* H          = (int*)alloc((size_t)NB * NC * 4);
  int* colTotal   = (int*)alloc((size_t)NB * 4);
  int* bucketBase = (int*)alloc((size_t)(NB + 1) * 4);
  int* tmp        = (int*)alloc((size_t)E * 4);
  int* csr_src    = (int*)alloc((size_t)E * 4);
  (void)ws_size; (void)in_sizes; (void)n_in; (void)out_size;

  // CSR build (atomic-free counting sort)
  p1_hist<<<NC, 256, 0, stream>>>(dst, H);
  p2_colscan<<<NB, 256, 0, stream>>>(H, colTotal);
  p3_bucketscan<<<1, 512, 0, stream>>>(colTotal, bucketBase);
  p4_scatter<<<NC, 256, 0, stream>>>(src, dst, H, bucketBase, tmp);
  p5_build<<<NB, 256, 0, stream>>>(tmp, bucketBase, rowstart, csr_src);

  int gemmGrid = (N + 63) / 64;
  int outGrid  = (N + 63) / 64;
  int aggGrid  = (N + 15) / 16;      // 16 nodes per 256-thread block

  // layer 1 (fp32 input x)
  gemm128_mfma<false><<<gemmGrid, 256, 0, stream>>>(x, W1, al1, ar1, hh, el, er, N);
  agg_fused<<<aggGrid, 256, 0, stream>>>(hh, el, er, rowstart, csr_src, b1, o16);

  // layer 2 (fp16 input o16)
  gemm128_mfma<true><<<gemmGrid, 256, 0, stream>>>(o16, W2, al2, ar2, hh, el, er, N);
  agg_fused<<<aggGrid, 256, 0, stream>>>(hh, el, er, rowstart, csr_src, b2, o16);

  // output linear (fp16 input, MFMA)
  gemm_out_k<<<outGrid, 256, 0, stream>>>(o16, Wout, bout, out, N);
}